// Round 6
// baseline (331.723 us; speedup 1.0000x reference)
//
#include <hip/hip_runtime.h>
#include <hip/hip_bf16.h>
#include <stdint.h>

typedef unsigned short u16;
using bf16x8 = __attribute__((ext_vector_type(8))) __bf16;
using f32x4  = __attribute__((ext_vector_type(4))) float;

// fp32 -> bf16 (round-to-nearest-even), as raw bits
__device__ __forceinline__ u16 f2bf(float f) {
    union { float f; unsigned u; } a; a.f = f;
    unsigned u = a.u;
    u += 0x7fffu + ((u >> 16) & 1u);
    return (u16)(u >> 16);
}
__device__ __forceinline__ float bf2f(unsigned bits_hi16) {
    union { unsigned u; float f; } a; a.u = bits_hi16; return a.f;
}

// async global->LDS, 16 bytes per lane (global_load_lds_dwordx4)
__device__ __forceinline__ void gload_lds16(const void* g, void* l) {
    __builtin_amdgcn_global_load_lds(
        (const __attribute__((address_space(1))) void*)g,
        (__attribute__((address_space(3))) void*)l, 16, 0, 0);
}

// ---------------------------------------------------------------------------
// Shared 128x128-tile bf16 GEMM core, C = A @ B^T
//   A:[M x lda] row-major (uses kLen cols), B:[N x ldb] row-major.
// 256 threads = 4 waves in 2x2; each wave does 64x64 via 4x4 tiles of 16x16x32.
// BK=32, LDS 128x32 bf16 per operand (8 KB each), global_load_lds width 16.
// ---------------------------------------------------------------------------
__device__ __forceinline__ void gemm_core(const u16* __restrict__ A,
                                          const u16* __restrict__ B,
                                          int lda, int ldb, int kLen,
                                          int bm, int bn,
                                          u16* sA, u16* sB,
                                          f32x4 acc[4][4])
{
    const int tid  = threadIdx.x;
    const int lane = tid & 63;
    const int wm   = (tid >> 7) & 1;
    const int wn   = (tid >> 6) & 1;

    const u16* Ag0 = A + (long)(bm * 128 + (tid >> 2)) * lda + (tid & 3) * 8;
    const u16* Ag1 = Ag0 + (long)64 * lda;
    const u16* Bg0 = B + (long)(bn * 128 + (tid >> 2)) * ldb + (tid & 3) * 8;
    const u16* Bg1 = Bg0 + (long)64 * ldb;
    u16* la0 = sA + tid * 8;
    u16* la1 = sA + 2048 + tid * 8;
    u16* lb0 = sB + tid * 8;
    u16* lb1 = sB + 2048 + tid * 8;

    const u16* ra = sA + (wm * 64 + (lane & 15)) * 32 + (lane >> 4) * 8;
    const u16* rb = sB + (wn * 64 + (lane & 15)) * 32 + (lane >> 4) * 8;

    for (int k0 = 0; k0 < kLen; k0 += 32) {
        gload_lds16(Ag0 + k0, la0);
        gload_lds16(Ag1 + k0, la1);
        gload_lds16(Bg0 + k0, lb0);
        gload_lds16(Bg1 + k0, lb1);
        __syncthreads();
        bf16x8 af[4], bfr[4];
#pragma unroll
        for (int i = 0; i < 4; i++) af[i]  = *(const bf16x8*)(ra + i * 512);
#pragma unroll
        for (int i = 0; i < 4; i++) bfr[i] = *(const bf16x8*)(rb + i * 512);
#pragma unroll
        for (int mi = 0; mi < 4; mi++)
#pragma unroll
            for (int ni = 0; ni < 4; ni++)
                acc[mi][ni] = __builtin_amdgcn_mfma_f32_16x16x32_bf16(
                    af[mi], bfr[ni], acc[mi][ni], 0, 0, 0);
        __syncthreads();
    }
}

// ---------------------------------------------------------------------------
// Kernel 1: fp32 -> bf16 casts for q,k,v (nqkv each) and Wq,Wk,Wv (nw each)
// ---------------------------------------------------------------------------
__global__ __launch_bounds__(256)
void cast6(const float* __restrict__ q, const float* __restrict__ k,
           const float* __restrict__ v, const float* __restrict__ wq,
           const float* __restrict__ wk, const float* __restrict__ wv,
           u16* __restrict__ qb, u16* __restrict__ kb, u16* __restrict__ vb,
           u16* __restrict__ wqb, u16* __restrict__ wkb, u16* __restrict__ wvb,
           int nqkv, int nw)
{
    const int z = blockIdx.y;
    const float* s; u16* d; int n;
    switch (z) {
        case 0:  s = q;  d = qb;  n = nqkv; break;
        case 1:  s = k;  d = kb;  n = nqkv; break;
        case 2:  s = v;  d = vb;  n = nqkv; break;
        case 3:  s = wq; d = wqb; n = nw;   break;
        case 4:  s = wk; d = wkb; n = nw;   break;
        default: s = wv; d = wvb; n = nw;   break;
    }
    long i = ((long)blockIdx.x * 256 + threadIdx.x) * 8;
    if (i >= n) return;
    float4 a = *(const float4*)(s + i);
    float4 b = *(const float4*)(s + i + 4);
    ushort4 o0, o1;
    o0.x = f2bf(a.x); o0.y = f2bf(a.y); o0.z = f2bf(a.z); o0.w = f2bf(a.w);
    o1.x = f2bf(b.x); o1.y = f2bf(b.y); o1.z = f2bf(b.z); o1.w = f2bf(b.w);
    *(ushort4*)(d + i)     = o0;
    *(ushort4*)(d + i + 4) = o1;
}

// ---------------------------------------------------------------------------
// Kernel 2: QK projections (launched with gridDim.z == 2; z=2 path unused).
//   z=0: qp = (q @ Wq^T + bq)*scale   z=1: kp = k @ Wk^T + bk
// ---------------------------------------------------------------------------
__global__ __launch_bounds__(256, 2)
void proj_gemm(const u16* __restrict__ qb, const u16* __restrict__ kb,
               const u16* __restrict__ vb, const u16* __restrict__ wqb,
               const u16* __restrict__ wkb, const u16* __restrict__ wvb,
               const float* __restrict__ bq, const float* __restrict__ bk,
               const float* __restrict__ bv,
               u16* __restrict__ qp, u16* __restrict__ kp, u16* __restrict__ vpT)
{
    __shared__ __align__(16) u16 sA[4096];
    __shared__ __align__(16) u16 sB[4096];
    const int z = blockIdx.z;
    const u16* A = (z == 0) ? qb : (z == 1) ? kb : vb;
    const u16* B = (z == 0) ? wqb : (z == 1) ? wkb : wvb;
    const float* bias = (z == 0) ? bq : (z == 1) ? bk : bv;
    u16* OUT = (z == 0) ? qp : (z == 1) ? kp : vpT;
    const float scale = (z == 0) ? 0.03125f : 1.0f;  // 1024^-0.5

    f32x4 acc[4][4] = {};
    gemm_core(A, B, 1024, 1024, 1024, blockIdx.y, blockIdx.x, sA, sB, acc);

    const int lane = threadIdx.x & 63;
    const int wm   = (threadIdx.x >> 7) & 1;
    const int wn   = (threadIdx.x >> 6) & 1;
    const int m0 = blockIdx.y * 128 + wm * 64 + ((lane >> 4) << 2);
    const int n0 = blockIdx.x * 128 + wn * 64 + (lane & 15);
#pragma unroll
    for (int mi = 0; mi < 4; mi++)
#pragma unroll
        for (int ni = 0; ni < 4; ni++) {
            const int gm = m0 + mi * 16;
            const int gn = n0 + ni * 16;
            const float bb = bias[gn];
#pragma unroll
            for (int r = 0; r < 4; r++) {
                float val = (acc[mi][ni][r] + bb) * scale;
                if (z < 2) OUT[(long)(gm + r) * 1024 + gn] = f2bf(val);
                else       OUT[(long)gn * 4096 + gm + r]   = f2bf(val);
            }
        }
}

// ---------------------------------------------------------------------------
// Kernel 2b: vpT = Wv @ v^T + bv (per-row)  [1024 x 4096] -- transpose-free.
// A = Wv [1024x1024], B = v [4096x1024], C[m,n] = vp[n,m]. Coalesced stores.
// Grid (32, 8): bn = blockIdx.x (N tiles), bm = blockIdx.y (M tiles).
// ---------------------------------------------------------------------------
__global__ __launch_bounds__(256, 2)
void vproj_gemm(const u16* __restrict__ wvb, const u16* __restrict__ vb,
                const float* __restrict__ bv, u16* __restrict__ vpT)
{
    __shared__ __align__(16) u16 sA[4096];
    __shared__ __align__(16) u16 sB[4096];
    f32x4 acc[4][4] = {};
    gemm_core(wvb, vb, 1024, 1024, 1024, blockIdx.y, blockIdx.x, sA, sB, acc);

    const int lane = threadIdx.x & 63;
    const int wm   = (threadIdx.x >> 7) & 1;
    const int wn   = (threadIdx.x >> 6) & 1;
    const int m0 = blockIdx.y * 128 + wm * 64 + ((lane >> 4) << 2);
    const int n0 = blockIdx.x * 128 + wn * 64 + (lane & 15);
#pragma unroll
    for (int mi = 0; mi < 4; mi++)
#pragma unroll
        for (int ni = 0; ni < 4; ni++) {
            const int gm = m0 + mi * 16;
            const int gn = n0 + ni * 16;
#pragma unroll
            for (int r = 0; r < 4; r++)
                vpT[(long)(gm + r) * 4096 + gn] = f2bf(acc[mi][ni][r] + bv[gm + r]);
        }
}

// ---------------------------------------------------------------------------
// Kernel 3: scores = qp @ kp^T  -> bf16 S, M=N=4096, K=1024
// ---------------------------------------------------------------------------
__global__ __launch_bounds__(256, 2)
void score_gemm(const u16* __restrict__ qp, const u16* __restrict__ kp,
                u16* __restrict__ S)
{
    __shared__ __align__(16) u16 sA[4096];
    __shared__ __align__(16) u16 sB[4096];
    f32x4 acc[4][4] = {};
    gemm_core(qp, kp, 1024, 1024, 1024, blockIdx.y, blockIdx.x, sA, sB, acc);

    const int lane = threadIdx.x & 63;
    const int wm   = (threadIdx.x >> 7) & 1;
    const int wn   = (threadIdx.x >> 6) & 1;
    const int m0 = blockIdx.y * 128 + wm * 64 + ((lane >> 4) << 2);
    const int n0 = blockIdx.x * 128 + wn * 64 + (lane & 15);
#pragma unroll
    for (int mi = 0; mi < 4; mi++)
#pragma unroll
        for (int ni = 0; ni < 4; ni++) {
            const int gm = m0 + mi * 16;
            const int gn = n0 + ni * 16;
#pragma unroll
            for (int r = 0; r < 4; r++)
                S[(long)(gm + r) * 4096 + gn] = f2bf(acc[mi][ni][r]);
        }
}

// ---------------------------------------------------------------------------
// Kernel 4: att = softmax(S_bf16, axis=-1) + bias, cast to bf16. Block per row.
// ---------------------------------------------------------------------------
__global__ __launch_bounds__(256)
void softmax_bias(const u16* __restrict__ S, const float* __restrict__ bias,
                  u16* __restrict__ att)
{
    const long row = blockIdx.x;
    const int tid = threadIdx.x;
    const u16* srow = S + row * 4096 + tid * 16;

    float v[16];
    {
        uint4 a = *(const uint4*)(srow);
        uint4 b = *(const uint4*)(srow + 8);
        unsigned w[8] = {a.x, a.y, a.z, a.w, b.x, b.y, b.z, b.w};
#pragma unroll
        for (int i = 0; i < 8; i++) {
            v[2 * i]     = bf2f(w[i] << 16);
            v[2 * i + 1] = bf2f(w[i] & 0xffff0000u);
        }
    }
    float mx = v[0];
#pragma unroll
    for (int i = 1; i < 16; i++) mx = fmaxf(mx, v[i]);
#pragma unroll
    for (int o = 32; o >= 1; o >>= 1) mx = fmaxf(mx, __shfl_xor(mx, o, 64));
    __shared__ float red[8];
    if ((tid & 63) == 0) red[tid >> 6] = mx;
    __syncthreads();
    mx = fmaxf(fmaxf(red[0], red[1]), fmaxf(red[2], red[3]));
    float sum = 0.f;
#pragma unroll
    for (int i = 0; i < 16; i++) { v[i] = __expf(v[i] - mx); sum += v[i]; }
#pragma unroll
    for (int o = 32; o >= 1; o >>= 1) sum += __shfl_xor(sum, o, 64);
    if ((tid & 63) == 0) red[4 + (tid >> 6)] = sum;
    __syncthreads();
    const float inv = 1.0f / (red[4] + red[5] + red[6] + red[7]);

    const float4* brow = (const float4*)(bias + row * 4096 + tid * 16);
    unsigned o[8];
#pragma unroll
    for (int i = 0; i < 4; i++) {
        float4 b = brow[i];
        unsigned lo = f2bf(v[4 * i + 0] * inv + b.x);
        unsigned hi = f2bf(v[4 * i + 1] * inv + b.y);
        o[2 * i] = lo | (hi << 16);
        lo = f2bf(v[4 * i + 2] * inv + b.z);
        hi = f2bf(v[4 * i + 3] * inv + b.w);
        o[2 * i + 1] = lo | (hi << 16);
    }
    u16* arow = att + row * 4096 + tid * 16;
    *(uint4*)(arow)     = make_uint4(o[0], o[1], o[2], o[3]);
    *(uint4*)(arow + 8) = make_uint4(o[4], o[5], o[6], o[7]);
}

// ---------------------------------------------------------------------------
// Kernel 5: split-K=4: P[z] = att[:, z*1024:(z+1)*1024] @ vpT[:, z*1024:..]^T
// M=4096, N=1024, K=1024 per split. Grid (8, 32, 4) = 1024 blocks = 4/CU.
// ---------------------------------------------------------------------------
__global__ __launch_bounds__(256, 2)
void out_gemm(const u16* __restrict__ att, const u16* __restrict__ vpT,
              float* __restrict__ P)
{
    __shared__ __align__(16) u16 sA[4096];
    __shared__ __align__(16) u16 sB[4096];
    const int z = blockIdx.z;
    const u16* A = att + z * 1024;
    const u16* B = vpT + z * 1024;
    float* O = P + (long)z * 4096 * 1024;

    f32x4 acc[4][4] = {};
    gemm_core(A, B, 4096, 4096, 1024, blockIdx.y, blockIdx.x, sA, sB, acc);

    const int lane = threadIdx.x & 63;
    const int wm   = (threadIdx.x >> 7) & 1;
    const int wn   = (threadIdx.x >> 6) & 1;
    const int m0 = blockIdx.y * 128 + wm * 64 + ((lane >> 4) << 2);
    const int n0 = blockIdx.x * 128 + wn * 64 + (lane & 15);
#pragma unroll
    for (int mi = 0; mi < 4; mi++)
#pragma unroll
        for (int ni = 0; ni < 4; ni++) {
            const int gm = m0 + mi * 16;
            const int gn = n0 + ni * 16;
#pragma unroll
            for (int r = 0; r < 4; r++)
                O[(long)(gm + r) * 1024 + gn] = acc[mi][ni][r];
        }
}

// ---------------------------------------------------------------------------
// Kernel 6: out = P0 + P1 + P2 + P3  (fp32), 4096x1024
// ---------------------------------------------------------------------------
__global__ __launch_bounds__(256)
void addp(const float* __restrict__ P, float* __restrict__ O)
{
    long i = ((long)blockIdx.x * 256 + threadIdx.x) * 4;
    const long STRIDE = 4194304;  // 4096*1024
    float4 a = *(const float4*)(P + i);
    float4 b = *(const float4*)(P + STRIDE + i);
    float4 c = *(const float4*)(P + 2 * STRIDE + i);
    float4 d = *(const float4*)(P + 3 * STRIDE + i);
    float4 r;
    r.x = (a.x + b.x) + (c.x + d.x);
    r.y = (a.y + b.y) + (c.y + d.y);
    r.z = (a.z + b.z) + (c.z + d.z);
    r.w = (a.w + b.w) + (c.w + d.w);
    *(float4*)(O + i) = r;
}

// ---------------------------------------------------------------------------
extern "C" void kernel_launch(void* const* d_in, const int* in_sizes, int n_in,
                              void* d_out, int out_size, void* d_ws, size_t ws_size,
                              hipStream_t stream)
{
    const float* q    = (const float*)d_in[0];
    const float* k    = (const float*)d_in[1];
    const float* v    = (const float*)d_in[2];
    const float* bias = (const float*)d_in[3];
    const float* Wq   = (const float*)d_in[4];
    const float* bq   = (const float*)d_in[5];
    const float* Wk   = (const float*)d_in[6];
    const float* bk   = (const float*)d_in[7];
    const float* Wv   = (const float*)d_in[8];
    const float* bv   = (const float*)d_in[9];
    float* out = (float*)d_out;

    uint8_t* ws = (uint8_t*)d_ws;
    const size_t MB = 1u << 20;
    // layout (peak 118 MB, same as R2/R5 known-good peak):
    //   [0,8)    qb   [8,16) kb   [16,24) vb        (dead after proj/vproj)
    //   [24,26)  wqb  [26,28) wkb [28,30) wvb       (dead after proj/vproj)
    //   [30,38)  qp   [38,46) kp                    (dead after score_gemm)
    //   [46,54)  vpT
    //   [54,86)  S (bf16 scores, 32MB)              (dead after softmax)
    //   [0,32)   att (bf16, 32MB) -- aliases dead qb/kb/vb region
    //   [54,118) P (4x fp32 partials, 16MB each) -- aliases dead S
    u16* qb  = (u16*)(ws);
    u16* kb  = (u16*)(ws + 8 * MB);
    u16* vb  = (u16*)(ws + 16 * MB);
    u16* wqb = (u16*)(ws + 24 * MB);
    u16* wkb = (u16*)(ws + 26 * MB);
    u16* wvb = (u16*)(ws + 28 * MB);
    u16* qp  = (u16*)(ws + 30 * MB);
    u16* kp  = (u16*)(ws + 38 * MB);
    u16* vpT = (u16*)(ws + 46 * MB);
    u16* S   = (u16*)(ws + 54 * MB);
    u16* att = (u16*)(ws);
    float* P = (float*)(ws + 54 * MB);

    cast6<<<dim3(2048, 6), 256, 0, stream>>>(q, k, v, Wq, Wk, Wv,
                                             qb, kb, vb, wqb, wkb, wvb,
                                             4096 * 1024, 1024 * 1024);
    proj_gemm<<<dim3(8, 32, 2), 256, 0, stream>>>(qb, kb, vb, wqb, wkb, wvb,
                                                  bq, bk, bv, qp, kp, vpT);
    vproj_gemm<<<dim3(32, 8), 256, 0, stream>>>(wvb, vb, bv, vpT);
    score_gemm<<<dim3(32, 32), 256, 0, stream>>>(qp, kp, S);
    softmax_bias<<<dim3(4096), 256, 0, stream>>>(S, bias, att);
    out_gemm<<<dim3(8, 32, 4), 256, 0, stream>>>(att, vpT, P);
    addp<<<dim3(4096), 256, 0, stream>>>(P, out);
}

// Round 7
// 307.634 us; speedup vs baseline: 1.0783x; 1.0783x over previous
//
#include <hip/hip_runtime.h>
#include <hip/hip_bf16.h>
#include <stdint.h>

typedef unsigned short u16;
using bf16x8 = __attribute__((ext_vector_type(8))) __bf16;
using f32x4  = __attribute__((ext_vector_type(4))) float;

// fp32 -> bf16 (round-to-nearest-even), as raw bits
__device__ __forceinline__ u16 f2bf(float f) {
    union { float f; unsigned u; } a; a.f = f;
    unsigned u = a.u;
    u += 0x7fffu + ((u >> 16) & 1u);
    return (u16)(u >> 16);
}
__device__ __forceinline__ float bf2f(unsigned bits_hi16) {
    union { unsigned u; float f; } a; a.u = bits_hi16; return a.f;
}

// async global->LDS, 16 bytes per lane (global_load_lds_dwordx4)
__device__ __forceinline__ void gload_lds16(const void* g, void* l) {
    __builtin_amdgcn_global_load_lds(
        (const __attribute__((address_space(1))) void*)g,
        (__attribute__((address_space(3))) void*)l, 16, 0, 0);
}

// ---------------------------------------------------------------------------
// Shared 128x128-tile bf16 GEMM core, C = A @ B^T
//   A:[M x lda] row-major (uses kLen cols), B:[N x ldb] row-major.
// 256 threads = 4 waves in 2x2; each wave does 64x64 via 4x4 tiles of 16x16x32.
// BK=64 per barrier: two side-by-side 128x32 LDS stages (same proven layout),
// 8 global_load_lds(16B) + one barrier pair per 64-K. LDS 16 KB per operand.
// kLen must be a multiple of 64.
// ---------------------------------------------------------------------------
__device__ __forceinline__ void gemm_core(const u16* __restrict__ A,
                                          const u16* __restrict__ B,
                                          int lda, int ldb, int kLen,
                                          int bm, int bn,
                                          u16* sA, u16* sB,
                                          f32x4 acc[4][4])
{
    const int tid  = threadIdx.x;
    const int lane = tid & 63;
    const int wm   = (tid >> 7) & 1;
    const int wn   = (tid >> 6) & 1;

    // staging (per 128x32 stage): thread t -> row=t>>2 (0..63), col8=(t&3)*8
    const u16* Ag0 = A + (long)(bm * 128 + (tid >> 2)) * lda + (tid & 3) * 8;
    const u16* Ag1 = Ag0 + (long)64 * lda;
    const u16* Bg0 = B + (long)(bn * 128 + (tid >> 2)) * ldb + (tid & 3) * 8;
    const u16* Bg1 = Bg0 + (long)64 * ldb;
    u16* la = sA + tid * 8;
    u16* lb = sB + tid * 8;

    // fragment read base within a stage: A[m=lane&15][k=(lane>>4)*8 + j]
    const int rfo = (wm * 64 + (lane & 15)) * 32 + (lane >> 4) * 8;
    const int rfoB = (wn * 64 + (lane & 15)) * 32 + (lane >> 4) * 8;

    for (int k0 = 0; k0 < kLen; k0 += 64) {
        // stage 0: k [k0, k0+32)
        gload_lds16(Ag0 + k0, la);
        gload_lds16(Ag1 + k0, la + 2048);
        gload_lds16(Bg0 + k0, lb);
        gload_lds16(Bg1 + k0, lb + 2048);
        // stage 1: k [k0+32, k0+64)
        gload_lds16(Ag0 + k0 + 32, la + 4096);
        gload_lds16(Ag1 + k0 + 32, la + 6144);
        gload_lds16(Bg0 + k0 + 32, lb + 4096);
        gload_lds16(Bg1 + k0 + 32, lb + 6144);
        __syncthreads();
#pragma unroll
        for (int h = 0; h < 2; h++) {
            const u16* ra = sA + h * 4096 + rfo;
            const u16* rb = sB + h * 4096 + rfoB;
            bf16x8 af[4], bfr[4];
#pragma unroll
            for (int i = 0; i < 4; i++) af[i]  = *(const bf16x8*)(ra + i * 512);
#pragma unroll
            for (int i = 0; i < 4; i++) bfr[i] = *(const bf16x8*)(rb + i * 512);
#pragma unroll
            for (int mi = 0; mi < 4; mi++)
#pragma unroll
                for (int ni = 0; ni < 4; ni++)
                    acc[mi][ni] = __builtin_amdgcn_mfma_f32_16x16x32_bf16(
                        af[mi], bfr[ni], acc[mi][ni], 0, 0, 0);
        }
        __syncthreads();
    }
}

// ---------------------------------------------------------------------------
// Kernel 1: fp32 -> bf16 casts for q,k,v (nqkv each) and Wq,Wk,Wv (nw each)
// ---------------------------------------------------------------------------
__global__ __launch_bounds__(256)
void cast6(const float* __restrict__ q, const float* __restrict__ k,
           const float* __restrict__ v, const float* __restrict__ wq,
           const float* __restrict__ wk, const float* __restrict__ wv,
           u16* __restrict__ qb, u16* __restrict__ kb, u16* __restrict__ vb,
           u16* __restrict__ wqb, u16* __restrict__ wkb, u16* __restrict__ wvb,
           int nqkv, int nw)
{
    const int z = blockIdx.y;
    const float* s; u16* d; int n;
    switch (z) {
        case 0:  s = q;  d = qb;  n = nqkv; break;
        case 1:  s = k;  d = kb;  n = nqkv; break;
        case 2:  s = v;  d = vb;  n = nqkv; break;
        case 3:  s = wq; d = wqb; n = nw;   break;
        case 4:  s = wk; d = wkb; n = nw;   break;
        default: s = wv; d = wvb; n = nw;   break;
    }
    long i = ((long)blockIdx.x * 256 + threadIdx.x) * 8;
    if (i >= n) return;
    float4 a = *(const float4*)(s + i);
    float4 b = *(const float4*)(s + i + 4);
    ushort4 o0, o1;
    o0.x = f2bf(a.x); o0.y = f2bf(a.y); o0.z = f2bf(a.z); o0.w = f2bf(a.w);
    o1.x = f2bf(b.x); o1.y = f2bf(b.y); o1.z = f2bf(b.z); o1.w = f2bf(b.w);
    *(ushort4*)(d + i)     = o0;
    *(ushort4*)(d + i + 4) = o1;
}

// ---------------------------------------------------------------------------
// Kernel 2: QK projections (launched with gridDim.z == 2; z=2 path unused).
//   z=0: qp = (q @ Wq^T + bq)*scale   z=1: kp = k @ Wk^T + bk
// ---------------------------------------------------------------------------
__global__ __launch_bounds__(256, 2)
void proj_gemm(const u16* __restrict__ qb, const u16* __restrict__ kb,
               const u16* __restrict__ vb, const u16* __restrict__ wqb,
               const u16* __restrict__ wkb, const u16* __restrict__ wvb,
               const float* __restrict__ bq, const float* __restrict__ bk,
               const float* __restrict__ bv,
               u16* __restrict__ qp, u16* __restrict__ kp, u16* __restrict__ vpT)
{
    __shared__ __align__(16) u16 sA[8192];
    __shared__ __align__(16) u16 sB[8192];
    const int z = blockIdx.z;
    const u16* A = (z == 0) ? qb : (z == 1) ? kb : vb;
    const u16* B = (z == 0) ? wqb : (z == 1) ? wkb : wvb;
    const float* bias = (z == 0) ? bq : (z == 1) ? bk : bv;
    u16* OUT = (z == 0) ? qp : (z == 1) ? kp : vpT;
    const float scale = (z == 0) ? 0.03125f : 1.0f;  // 1024^-0.5

    f32x4 acc[4][4] = {};
    gemm_core(A, B, 1024, 1024, 1024, blockIdx.y, blockIdx.x, sA, sB, acc);

    const int lane = threadIdx.x & 63;
    const int wm   = (threadIdx.x >> 7) & 1;
    const int wn   = (threadIdx.x >> 6) & 1;
    const int m0 = blockIdx.y * 128 + wm * 64 + ((lane >> 4) << 2);
    const int n0 = blockIdx.x * 128 + wn * 64 + (lane & 15);
#pragma unroll
    for (int mi = 0; mi < 4; mi++)
#pragma unroll
        for (int ni = 0; ni < 4; ni++) {
            const int gm = m0 + mi * 16;
            const int gn = n0 + ni * 16;
            const float bb = bias[gn];
#pragma unroll
            for (int r = 0; r < 4; r++) {
                float val = (acc[mi][ni][r] + bb) * scale;
                if (z < 2) OUT[(long)(gm + r) * 1024 + gn] = f2bf(val);
                else       OUT[(long)gn * 4096 + gm + r]   = f2bf(val);
            }
        }
}

// ---------------------------------------------------------------------------
// Kernel 2b: vpT = Wv @ v^T + bv (per-row)  [1024 x 4096] -- transpose-free.
// A = Wv [1024x1024], B = v [4096x1024], C[m,n] = vp[n,m]. Coalesced stores.
// Grid (32, 8): bn = blockIdx.x (N tiles), bm = blockIdx.y (M tiles).
// ---------------------------------------------------------------------------
__global__ __launch_bounds__(256, 2)
void vproj_gemm(const u16* __restrict__ wvb, const u16* __restrict__ vb,
                const float* __restrict__ bv, u16* __restrict__ vpT)
{
    __shared__ __align__(16) u16 sA[8192];
    __shared__ __align__(16) u16 sB[8192];
    f32x4 acc[4][4] = {};
    gemm_core(wvb, vb, 1024, 1024, 1024, blockIdx.y, blockIdx.x, sA, sB, acc);

    const int lane = threadIdx.x & 63;
    const int wm   = (threadIdx.x >> 7) & 1;
    const int wn   = (threadIdx.x >> 6) & 1;
    const int m0 = blockIdx.y * 128 + wm * 64 + ((lane >> 4) << 2);
    const int n0 = blockIdx.x * 128 + wn * 64 + (lane & 15);
#pragma unroll
    for (int mi = 0; mi < 4; mi++)
#pragma unroll
        for (int ni = 0; ni < 4; ni++) {
            const int gm = m0 + mi * 16;
            const int gn = n0 + ni * 16;
#pragma unroll
            for (int r = 0; r < 4; r++)
                vpT[(long)(gm + r) * 4096 + gn] = f2bf(acc[mi][ni][r] + bv[gm + r]);
        }
}

// ---------------------------------------------------------------------------
// Kernel 3: scores = qp @ kp^T  -> bf16 S, M=N=4096, K=1024
// ---------------------------------------------------------------------------
__global__ __launch_bounds__(256, 2)
void score_gemm(const u16* __restrict__ qp, const u16* __restrict__ kp,
                u16* __restrict__ S)
{
    __shared__ __align__(16) u16 sA[8192];
    __shared__ __align__(16) u16 sB[8192];
    f32x4 acc[4][4] = {};
    gemm_core(qp, kp, 1024, 1024, 1024, blockIdx.y, blockIdx.x, sA, sB, acc);

    const int lane = threadIdx.x & 63;
    const int wm   = (threadIdx.x >> 7) & 1;
    const int wn   = (threadIdx.x >> 6) & 1;
    const int m0 = blockIdx.y * 128 + wm * 64 + ((lane >> 4) << 2);
    const int n0 = blockIdx.x * 128 + wn * 64 + (lane & 15);
#pragma unroll
    for (int mi = 0; mi < 4; mi++)
#pragma unroll
        for (int ni = 0; ni < 4; ni++) {
            const int gm = m0 + mi * 16;
            const int gn = n0 + ni * 16;
#pragma unroll
            for (int r = 0; r < 4; r++)
                S[(long)(gm + r) * 4096 + gn] = f2bf(acc[mi][ni][r]);
        }
}

// ---------------------------------------------------------------------------
// Kernel 4: att = softmax(S_bf16, axis=-1) + bias, cast to bf16. Block per row.
// ---------------------------------------------------------------------------
__global__ __launch_bounds__(256)
void softmax_bias(const u16* __restrict__ S, const float* __restrict__ bias,
                  u16* __restrict__ att)
{
    const long row = blockIdx.x;
    const int tid = threadIdx.x;
    const u16* srow = S + row * 4096 + tid * 16;

    float v[16];
    {
        uint4 a = *(const uint4*)(srow);
        uint4 b = *(const uint4*)(srow + 8);
        unsigned w[8] = {a.x, a.y, a.z, a.w, b.x, b.y, b.z, b.w};
#pragma unroll
        for (int i = 0; i < 8; i++) {
            v[2 * i]     = bf2f(w[i] << 16);
            v[2 * i + 1] = bf2f(w[i] & 0xffff0000u);
        }
    }
    float mx = v[0];
#pragma unroll
    for (int i = 1; i < 16; i++) mx = fmaxf(mx, v[i]);
#pragma unroll
    for (int o = 32; o >= 1; o >>= 1) mx = fmaxf(mx, __shfl_xor(mx, o, 64));
    __shared__ float red[8];
    if ((tid & 63) == 0) red[tid >> 6] = mx;
    __syncthreads();
    mx = fmaxf(fmaxf(red[0], red[1]), fmaxf(red[2], red[3]));
    float sum = 0.f;
#pragma unroll
    for (int i = 0; i < 16; i++) { v[i] = __expf(v[i] - mx); sum += v[i]; }
#pragma unroll
    for (int o = 32; o >= 1; o >>= 1) sum += __shfl_xor(sum, o, 64);
    if ((tid & 63) == 0) red[4 + (tid >> 6)] = sum;
    __syncthreads();
    const float inv = 1.0f / (red[4] + red[5] + red[6] + red[7]);

    const float4* brow = (const float4*)(bias + row * 4096 + tid * 16);
    unsigned o[8];
#pragma unroll
    for (int i = 0; i < 4; i++) {
        float4 b = brow[i];
        unsigned lo = f2bf(v[4 * i + 0] * inv + b.x);
        unsigned hi = f2bf(v[4 * i + 1] * inv + b.y);
        o[2 * i] = lo | (hi << 16);
        lo = f2bf(v[4 * i + 2] * inv + b.z);
        hi = f2bf(v[4 * i + 3] * inv + b.w);
        o[2 * i + 1] = lo | (hi << 16);
    }
    u16* arow = att + row * 4096 + tid * 16;
    *(uint4*)(arow)     = make_uint4(o[0], o[1], o[2], o[3]);
    *(uint4*)(arow + 8) = make_uint4(o[4], o[5], o[6], o[7]);
}

// ---------------------------------------------------------------------------
// Kernel 5: split-K=2: P[z] = att[:, z*2048:(z+1)*2048] @ vpT[:, z*2048:..]^T
// M=4096, N=1024, K=2048 per split. Grid (8, 32, 2) = 512 blocks.
// ---------------------------------------------------------------------------
__global__ __launch_bounds__(256, 2)
void out_gemm(const u16* __restrict__ att, const u16* __restrict__ vpT,
              float* __restrict__ P)
{
    __shared__ __align__(16) u16 sA[8192];
    __shared__ __align__(16) u16 sB[8192];
    const int z = blockIdx.z;
    const u16* A = att + z * 2048;
    const u16* B = vpT + z * 2048;
    float* O = P + (long)z * 4096 * 1024;

    f32x4 acc[4][4] = {};
    gemm_core(A, B, 4096, 4096, 2048, blockIdx.y, blockIdx.x, sA, sB, acc);

    const int lane = threadIdx.x & 63;
    const int wm   = (threadIdx.x >> 7) & 1;
    const int wn   = (threadIdx.x >> 6) & 1;
    const int m0 = blockIdx.y * 128 + wm * 64 + ((lane >> 4) << 2);
    const int n0 = blockIdx.x * 128 + wn * 64 + (lane & 15);
#pragma unroll
    for (int mi = 0; mi < 4; mi++)
#pragma unroll
        for (int ni = 0; ni < 4; ni++) {
            const int gm = m0 + mi * 16;
            const int gn = n0 + ni * 16;
#pragma unroll
            for (int r = 0; r < 4; r++)
                O[(long)(gm + r) * 1024 + gn] = acc[mi][ni][r];
        }
}

// ---------------------------------------------------------------------------
// Kernel 6: out = P0 + P1  (fp32), 4096x1024
// ---------------------------------------------------------------------------
__global__ __launch_bounds__(256)
void addp(const float* __restrict__ P, float* __restrict__ O)
{
    long i = ((long)blockIdx.x * 256 + threadIdx.x) * 4;
    float4 a = *(const float4*)(P + i);
    float4 b = *(const float4*)(P + 4194304 + i);
    float4 r;
    r.x = a.x + b.x; r.y = a.y + b.y; r.z = a.z + b.z; r.w = a.w + b.w;
    *(float4*)(O + i) = r;
}

// ---------------------------------------------------------------------------
extern "C" void kernel_launch(void* const* d_in, const int* in_sizes, int n_in,
                              void* d_out, int out_size, void* d_ws, size_t ws_size,
                              hipStream_t stream)
{
    const float* q    = (const float*)d_in[0];
    const float* k    = (const float*)d_in[1];
    const float* v    = (const float*)d_in[2];
    const float* bias = (const float*)d_in[3];
    const float* Wq   = (const float*)d_in[4];
    const float* bq   = (const float*)d_in[5];
    const float* Wk   = (const float*)d_in[6];
    const float* bk   = (const float*)d_in[7];
    const float* Wv   = (const float*)d_in[8];
    const float* bv   = (const float*)d_in[9];
    float* out = (float*)d_out;

    uint8_t* ws = (uint8_t*)d_ws;
    const size_t MB = 1u << 20;
    // layout (118 MB), identical to the R5 known-good run:
    //   [0,8)    qb   [8,16) kb   [16,24) vb        (dead after proj/vproj)
    //   [24,26)  wqb  [26,28) wkb [28,30) wvb       (dead after proj/vproj)
    //   [30,38)  qp   [38,46) kp                    (dead after score_gemm)
    //   [46,54)  vpT
    //   [54,86)  S (bf16 scores, 32MB)              (dead after softmax)
    //   [0,32)   att (bf16, 32MB) -- aliases dead qb/kb/vb region
    //   [86,118) P (2x fp32 partials, 16MB each)
    u16* qb  = (u16*)(ws);
    u16* kb  = (u16*)(ws + 8 * MB);
    u16* vb  = (u16*)(ws + 16 * MB);
    u16* wqb = (u16*)(ws + 24 * MB);
    u16* wkb = (u16*)(ws + 26 * MB);
    u16* wvb = (u16*)(ws + 28 * MB);
    u16* qp  = (u16*)(ws + 30 * MB);
    u16* kp  = (u16*)(ws + 38 * MB);
    u16* vpT = (u16*)(ws + 46 * MB);
    u16* S   = (u16*)(ws + 54 * MB);
    u16* att = (u16*)(ws);
    float* P = (float*)(ws + 86 * MB);

    cast6<<<dim3(2048, 6), 256, 0, stream>>>(q, k, v, Wq, Wk, Wv,
                                             qb, kb, vb, wqb, wkb, wvb,
                                             4096 * 1024, 1024 * 1024);
    proj_gemm<<<dim3(8, 32, 2), 256, 0, stream>>>(qb, kb, vb, wqb, wkb, wvb,
                                                  bq, bk, bv, qp, kp, vpT);
    vproj_gemm<<<dim3(32, 8), 256, 0, stream>>>(wvb, vb, bv, vpT);
    score_gemm<<<dim3(32, 32), 256, 0, stream>>>(qp, kp, S);
    softmax_bias<<<dim3(4096), 256, 0, stream>>>(S, bias, att);
    out_gemm<<<dim3(8, 32, 2), 256, 0, stream>>>(att, vpT, P);
    addp<<<dim3(4096), 256, 0, stream>>>(P, out);
}